// Round 2
// baseline (1483.012 us; speedup 1.0000x reference)
//
#include <hip/hip_runtime.h>
#include <hip/hip_bf16.h>

// CNF: hypernet(t) -> (W,B,U) per time; RK4 integrate z (N=65536, D=8) and logp.
// All I/O fp32 (per reference dtypes). 63 distinct hypernet times precomputed
// into ws as fp32:
//   per slot: 128 rows of [W[w][0..7], U_gated[w][0..7]] (2048 f)
//             + 128 x [B[w], dot(W_w,U_w)] (256 f)   -> PSTRIDE = 2304 floats
// Main kernel: 1 thread = 1 sample; params are wave-uniform -> scalar loads.

#define DD 8
#define HIDDEN 64
#define WIDTH 128
#define NSAMP 65536
#define TT 8
#define PSTRIDE 2304
#define NSLOT 63       // 7 segments * 9 distinct times

__device__ __forceinline__ float tanh_fast(float x) {
    // tanh(x) = 1 - 2/(exp(2x)+1);  exp(2x) = exp2(x * 2*log2(e))
    float e = __builtin_amdgcn_exp2f(x * 2.88539008177792681472f);
    float r = __builtin_amdgcn_rcpf(e + 1.0f);
    return __builtin_fmaf(-2.0f, r, 1.0f);
}

__device__ __forceinline__ float sigmoid_fast(float x) {
    float e = __builtin_amdgcn_exp2f(x * -1.44269504088896340736f);
    return __builtin_amdgcn_rcpf(e + 1.0f);
}

__global__ __launch_bounds__(256) void cnf_hyper(
    const float* __restrict__ ts,
    const float* __restrict__ w1,
    const float* __restrict__ b1,
    const float* __restrict__ w2,
    const float* __restrict__ b2,
    const float* __restrict__ w3,
    const float* __restrict__ b3,
    float* __restrict__ params)
{
    const int slot = blockIdx.x;          // 0..62
    const int seg = slot / 9;
    const int j = slot % 9;
    const float t0 = ts[seg];
    const float t1 = ts[seg + 1];
    const float dt = (t1 - t0) * 0.25f;
    // Replicate the reference's accumulated-addition time chain.
    float t = t0;
    const int na = (j < 4) ? j : ((j < 8) ? (j - 4) : 4);
    for (int i = 0; i < na; ++i) t += dt;
    if (j >= 4 && j < 8) t += dt * 0.5f;

    __shared__ float h1s[HIDDEN];
    __shared__ float h2s[HIDDEN];
    __shared__ float pbuf[3 * WIDTH * DD + WIDTH];  // 3200

    const int tid = threadIdx.x;
    if (tid < HIDDEN) {
        h1s[tid] = tanh_fast(__builtin_fmaf(w1[tid], t, b1[tid]));
    }
    __syncthreads();
    if (tid < HIDDEN) {
        float a = b2[tid];
        #pragma unroll 8
        for (int k = 0; k < HIDDEN; ++k)
            a = __builtin_fmaf(w2[tid * HIDDEN + k], h1s[k], a);
        h2s[tid] = tanh_fast(a);
    }
    __syncthreads();
    for (int r = tid; r < 3200; r += 256) {
        float a = b3[r];
        const float* wr = w3 + (size_t)r * HIDDEN;
        #pragma unroll 8
        for (int k = 0; k < HIDDEN; ++k)
            a = __builtin_fmaf(wr[k], h2s[k], a);
        pbuf[r] = a;
    }
    __syncthreads();
    if (tid < WIDTH) {
        const int w = tid;
        float* dst = params + (size_t)slot * PSTRIDE + w * 16;
        float dot = 0.0f;
        #pragma unroll
        for (int d = 0; d < DD; ++d) {
            float Wd = pbuf[w * DD + d];
            float Ud = pbuf[WIDTH * DD + w * DD + d] *
                       sigmoid_fast(pbuf[2 * WIDTH * DD + w * DD + d]);
            dst[d] = Wd;
            dst[8 + d] = Ud;
            dot = __builtin_fmaf(Wd, Ud, dot);
        }
        float* bd = params + (size_t)slot * PSTRIDE + 2048;
        bd[2 * w] = pbuf[3 * WIDTH * DD + w];
        bd[2 * w + 1] = dot;
    }
}

__device__ __forceinline__ void rhs_eval(const float* __restrict__ p,
                                         const float z[DD], float f[DD], float* kl)
{
    #pragma unroll
    for (int d = 0; d < DD; ++d) f[d] = 0.0f;
    float tr = 0.0f;
    const float* __restrict__ bd = p + 2048;
    #pragma unroll 4
    for (int w = 0; w < WIDTH; ++w) {
        const float* __restrict__ row = p + w * 16;
        float a = bd[2 * w];
        #pragma unroll
        for (int d = 0; d < DD; ++d) a = __builtin_fmaf(row[d], z[d], a);
        float th = tanh_fast(a);
        #pragma unroll
        for (int d = 0; d < DD; ++d) f[d] = __builtin_fmaf(th, row[8 + d], f[d]);
        tr = __builtin_fmaf(__builtin_fmaf(-th, th, 1.0f), bd[2 * w + 1], tr);
    }
    const float inv = 1.0f / (float)WIDTH;
    #pragma unroll
    for (int d = 0; d < DD; ++d) f[d] *= inv;
    *kl = -tr * inv;
}

__global__ __launch_bounds__(256) void cnf_integrate(
    const float* __restrict__ ts,
    const float* __restrict__ z0,
    const float* __restrict__ lp0,
    const float* __restrict__ params,
    float* __restrict__ out)
{
    const int n = blockIdx.x * 256 + threadIdx.x;
    const size_t LPBASE = (size_t)TT * NSAMP * DD;  // 4194304

    float z[DD], acc[DD], zin[DD], f[DD];
    #pragma unroll
    for (int d = 0; d < DD; ++d) z[d] = z0[(size_t)n * DD + d];
    float lp = lp0[n];

    // t=0 outputs
    #pragma unroll
    for (int d = 0; d < DD; ++d)
        out[(size_t)n * DD + d] = z[d];
    out[LPBASE + n] = lp;

    for (int seg = 0; seg < TT - 1; ++seg) {
        const float t0 = ts[seg];
        const float t1 = ts[seg + 1];
        const float dt = (t1 - t0) * 0.25f;
        const float c6 = dt * (1.0f / 6.0f);
        const float c3 = dt * (1.0f / 3.0f);
        const float h2 = dt * 0.5f;
        const float* segp = params + (size_t)seg * 9 * PSTRIDE;

        for (int s = 0; s < 4; ++s) {
            const float* pa = segp + (size_t)s * PSTRIDE;           // t
            const float* pb = segp + (size_t)(4 + s) * PSTRIDE;     // t + dt/2
            const float* pc = segp + (size_t)((s < 3) ? (s + 1) : 8) * PSTRIDE; // t + dt
            float kl, lacc;
            // k1
            rhs_eval(pa, z, f, &kl);
            #pragma unroll
            for (int d = 0; d < DD; ++d) {
                acc[d] = __builtin_fmaf(c6, f[d], z[d]);
                zin[d] = __builtin_fmaf(h2, f[d], z[d]);
            }
            lacc = __builtin_fmaf(c6, kl, lp);
            // k2
            rhs_eval(pb, zin, f, &kl);
            #pragma unroll
            for (int d = 0; d < DD; ++d) {
                acc[d] = __builtin_fmaf(c3, f[d], acc[d]);
                zin[d] = __builtin_fmaf(h2, f[d], z[d]);
            }
            lacc = __builtin_fmaf(c3, kl, lacc);
            // k3
            rhs_eval(pb, zin, f, &kl);
            #pragma unroll
            for (int d = 0; d < DD; ++d) {
                acc[d] = __builtin_fmaf(c3, f[d], acc[d]);
                zin[d] = __builtin_fmaf(dt, f[d], z[d]);
            }
            lacc = __builtin_fmaf(c3, kl, lacc);
            // k4
            rhs_eval(pc, zin, f, &kl);
            #pragma unroll
            for (int d = 0; d < DD; ++d)
                z[d] = __builtin_fmaf(c6, f[d], acc[d]);
            lp = __builtin_fmaf(c6, kl, lacc);
        }
        // outputs at time index seg+1
        const size_t zo = (size_t)(seg + 1) * NSAMP * DD + (size_t)n * DD;
        #pragma unroll
        for (int d = 0; d < DD; ++d) out[zo + d] = z[d];
        out[LPBASE + (size_t)(seg + 1) * NSAMP + n] = lp;
    }
}

extern "C" void kernel_launch(void* const* d_in, const int* in_sizes, int n_in,
                              void* d_out, int out_size, void* d_ws, size_t ws_size,
                              hipStream_t stream) {
    const float* ts  = (const float*)d_in[0];
    const float* z0  = (const float*)d_in[1];
    const float* lp0 = (const float*)d_in[2];
    const float* w1  = (const float*)d_in[3];
    const float* b1  = (const float*)d_in[4];
    const float* w2  = (const float*)d_in[5];
    const float* b2  = (const float*)d_in[6];
    const float* w3  = (const float*)d_in[7];
    const float* b3  = (const float*)d_in[8];
    float* params = (float*)d_ws;  // 63 * 2304 * 4 B = 580,608 B

    cnf_hyper<<<dim3(NSLOT), dim3(256), 0, stream>>>(ts, w1, b1, w2, b2, w3, b3, params);
    cnf_integrate<<<dim3(NSAMP / 256), dim3(256), 0, stream>>>(
        ts, z0, lp0, params, (float*)d_out);
}